// Round 1
// 1661.501 us; speedup vs baseline: 1.0695x; 1.0695x over previous
//
#include <hip/hip_runtime.h>
#include <math.h>

#define N_NODES 50000
#define N_EDGES 640000
#define INF_ 64
#define DD 96
#define HH 384
#define NLAYERS 4
#define NGRAPH 512
#define NOUT_ 2
#define MAXDEG 64

#define ACT_NONE 0
#define ACT_RELU 1
#define ACT_ELU 2
#define ACT_LEAKY 3

typedef unsigned int uint;
typedef unsigned short ushort;
typedef __attribute__((ext_vector_type(8))) short v8s;   // 8 bf16 (4 VGPRs)
typedef __attribute__((ext_vector_type(4))) float v4f;   // 4 fp32 acc

__device__ __forceinline__ float bf_lo(uint u) { return __uint_as_float(u << 16); }
__device__ __forceinline__ float bf_hi(uint u) { return __uint_as_float(u & 0xffff0000u); }
__device__ __forceinline__ float bfs(ushort s) { return __uint_as_float(((uint)s) << 16); }
__device__ __forceinline__ ushort f2bf(float f)
{
    uint u = __float_as_uint(f);
    return (ushort)((u + 0x7fffu + ((u >> 16) & 1u)) >> 16);
}

// ================= MFMA bf16 GEMM: C = act(A@B (+bias) (+C)) =================
// A: M x K bf16 row-major. Bt: N x K bf16 row-major (pre-transposed weights).
// BM=128, 256 thr = 4 waves (2x2), wave tile 64 x BN/2. K % 32 == 0, Nc % BN == 0.
template<int BN, int ACT, bool ACCUM, bool OUT16>
__global__ __launch_bounds__(256)
void gemm_mf(const ushort* __restrict__ A, const ushort* __restrict__ Bt,
             const float* __restrict__ bias, float* __restrict__ C32,
             ushort* __restrict__ C16, int M, int Nc, int K)
{
    const int BM = 128, LDA = 40;      // 32 + 8 pad (bf16 units) -> 2-way b128, free
    const int FN = BN / 32;            // n-fragments per wave
    __shared__ ushort As[BM * LDA];
    __shared__ ushort Bs[BN * LDA];
    int tid = threadIdx.x;
    int lane = tid & 63, wave = tid >> 6;
    int ln15 = lane & 15, quad = lane >> 4;
    int wm = (wave >> 1) * 64, wn = (wave & 1) * (BN / 2);
    int bm0 = blockIdx.x * BM, bn0 = blockIdx.y * BN;

    v4f acc[4][FN];
    #pragma unroll
    for (int i = 0; i < 4; i++)
        #pragma unroll
        for (int j = 0; j < FN; j++) acc[i][j] = (v4f){0.f, 0.f, 0.f, 0.f};

    for (int k0 = 0; k0 < K; k0 += 32) {
        #pragma unroll
        for (int it = 0; it < 2; it++) {
            int u = it * 256 + tid;
            int r = u >> 2, c8 = (u & 3) * 8;
            int row = bm0 + r;
            int4 v = make_int4(0, 0, 0, 0);
            if (row < M) v = *(const int4*)&A[(size_t)row * K + k0 + c8];
            *(int4*)&As[r * LDA + c8] = v;
        }
        #pragma unroll
        for (int it = 0; it < (BN * 4 + 255) / 256; it++) {
            int u = it * 256 + tid;
            if ((BN * 4) % 256 == 0 || u < BN * 4) {
                int r = u >> 2, c8 = (u & 3) * 8;
                *(int4*)&Bs[r * LDA + c8] =
                    *(const int4*)&Bt[(size_t)(bn0 + r) * K + k0 + c8];
            }
        }
        __syncthreads();
        v8s af[4], bf[FN];
        #pragma unroll
        for (int i = 0; i < 4; i++)
            af[i] = *(const v8s*)&As[(wm + i * 16 + ln15) * LDA + quad * 8];
        #pragma unroll
        for (int j = 0; j < FN; j++)
            bf[j] = *(const v8s*)&Bs[(wn + j * 16 + ln15) * LDA + quad * 8];
        #pragma unroll
        for (int i = 0; i < 4; i++)
            #pragma unroll
            for (int j = 0; j < FN; j++)
                acc[i][j] = __builtin_amdgcn_mfma_f32_16x16x32_bf16(
                    af[i], bf[j], acc[i][j], 0, 0, 0);
        __syncthreads();
    }
    #pragma unroll
    for (int i = 0; i < 4; i++) {
        #pragma unroll
        for (int j = 0; j < FN; j++) {
            int col = bn0 + wn + j * 16 + ln15;
            float bsv = bias ? bias[col] : 0.f;
            #pragma unroll
            for (int r = 0; r < 4; r++) {
                int row = bm0 + wm + i * 16 + quad * 4 + r;
                if (row >= M) continue;
                float v = acc[i][j][r] + bsv;
                if (ACCUM) v += C32[(size_t)row * Nc + col];
                if (ACT == ACT_RELU)       v = fmaxf(v, 0.f);
                else if (ACT == ACT_ELU)   v = v > 0.f ? v : expm1f(v);
                else if (ACT == ACT_LEAKY) v = v > 0.f ? v : 0.01f * v;
                if (OUT16) C16[(size_t)row * Nc + col] = f2bf(v);
                else       C32[(size_t)row * Nc + col] = v;
            }
        }
    }
}

__device__ __forceinline__ float wave_reduce_sum(float v)
{
    #pragma unroll
    for (int o = 32; o > 0; o >>= 1) v += __shfl_xor(v, o, 64);
    return v;
}

// ---------------- fp32 -> bf16 convert ----------------
__global__ __launch_bounds__(256)
void cvt16(const float* __restrict__ in, ushort* __restrict__ out, long n)
{
    long i = ((long)blockIdx.x * 256 + threadIdx.x) * 4;
    if (i >= n) return;
    float4 v = *(const float4*)&in[i];
    ushort4 o;
    o.x = f2bf(v.x); o.y = f2bf(v.y); o.z = f2bf(v.z); o.w = f2bf(v.w);
    *(ushort4*)&out[i] = o;
}

// ---------------- Wqk = Wq@Wk^T, bqk = bq@Wk^T -> Wcat cols 288..383 (fp32) ----------
__global__ __launch_bounds__(256)
void wqk_k(const float* __restrict__ Wq, const float* __restrict__ Wk,
           const float* __restrict__ bq, float* __restrict__ Wcat, float* __restrict__ bcat)
{
    int l = blockIdx.y;
    int idx = blockIdx.x * 256 + threadIdx.x;
    const float* wq = Wq + (size_t)l * DD * DD;
    const float* wk = Wk + (size_t)l * DD * DD;
    if (idx < DD * DD) {
        int k = idx / DD, j = idx % DD;
        float s = 0.f;
        for (int t = 0; t < DD; t++) s += wq[k * DD + t] * wk[j * DD + t];
        Wcat[(size_t)l * DD * 4 * DD + (size_t)k * 4 * DD + 288 + j] = s;
    }
    if (idx < DD) {
        int j = idx;
        float s = 0.f;
        for (int t = 0; t < DD; t++) s += bq[l * DD + t] * wk[j * DD + t];
        bcat[l * 4 * DD + 288 + j] = s;
    }
}

// ---------------- pack [Wq|Wk|Wv] into Wcat cols 0..287 + biases (fp32) ----------------
__global__ __launch_bounds__(256)
void pack_k(const float* __restrict__ Wq, const float* __restrict__ Wk,
            const float* __restrict__ Wv, const float* __restrict__ bq,
            const float* __restrict__ bk, const float* __restrict__ bv,
            float* __restrict__ Wcat, float* __restrict__ bcat)
{
    int idx = blockIdx.x * 256 + threadIdx.x;
    if (idx >= NLAYERS * DD * 288) return;
    int l = idx / (DD * 288);
    int rem = idx % (DD * 288);
    int k = rem / 288, n = rem % 288;
    int which = n / DD, j = n % DD;
    const float* W = which == 0 ? Wq : (which == 1 ? Wk : Wv);
    Wcat[(size_t)l * DD * 4 * DD + (size_t)k * 4 * DD + n] =
        W[(size_t)l * DD * DD + k * DD + j];
    if (k == 0) {
        const float* bb = which == 0 ? bq : (which == 1 ? bk : bv);
        bcat[l * 4 * DD + n] = bb[l * DD + j];
    }
}

// ---------------- transpose+convert all weights: src KxN fp32 -> dst NxK bf16 ----------
#define NPACK 22
struct PackArgs {
    const float* src[NPACK];
    ushort* dst[NPACK];
    int K[NPACK], N[NPACK];
};
__global__ __launch_bounds__(256)
void packT_k(PackArgs pa)
{
    int w = blockIdx.y;
    int K = pa.K[w], N = pa.N[w];
    int idx = blockIdx.x * 256 + threadIdx.x;
    if (idx >= K * N) return;
    int n = idx / K, k = idx % K;           // write-coalesced
    pa.dst[w][(size_t)n * K + k] = f2bf(pa.src[w][(size_t)k * N + n]);
}

// ---------------- adjacency build (padded slots) ----------------
__global__ __launch_bounds__(256)
void scatter_k(const int* __restrict__ src, const int* __restrict__ dst,
               int* __restrict__ deg, int2* __restrict__ pe)
{
    int e = blockIdx.x * 256 + threadIdx.x;
    if (e >= N_EDGES) return;
    int d = dst[e];
    int c = atomicAdd(&deg[d], 1);
    if (c < MAXDEG) pe[(size_t)d * MAXDEG + c] = make_int2(src[e], e);
}

// qkv16 row layout (bf16, stride 384): [0:96]=Q [96:192]=K [192:288]=V [288:384]=Qk
// One 64-lane wave per dst node; halves (lanes 0-31 / 32-63) process two edges
// concurrently, unrolled x2 -> 4 edges in flight per wave.
template<bool EA16>
__global__ __launch_bounds__(256)
void edge1w(const ushort* __restrict__ qkv16, const void* __restrict__ eaP,
            const int2* __restrict__ pe, const int* __restrict__ deg,
            float* __restrict__ ae_slot, float* __restrict__ denom, float scale)
{
    int lane = threadIdx.x & 63;
    int half = lane >> 5, l32 = lane & 31;
    int d = blockIdx.x * 4 + (threadIdx.x >> 6);
    if (d >= N_NODES) return;
    int cnt = deg[d]; if (cnt > MAXDEG) cnt = MAXDEG;
    if (cnt == 0) return;
    const uint* qrow = (const uint*)(qkv16 + (size_t)d * 384);
    const uint* prow = (const uint*)(qkv16 + (size_t)d * 384 + 288);
    uint qu0 = qrow[l32], pu0 = prow[l32];
    uint qu1 = 0, pu1 = 0;
    if (l32 < 16) { qu1 = qrow[32 + l32]; pu1 = prow[32 + l32]; }
    float q00 = bf_lo(qu0), q01 = bf_hi(qu0), q10 = bf_lo(qu1), q11 = bf_hi(qu1);
    float p00 = bf_lo(pu0), p01 = bf_hi(pu0), p10 = bf_lo(pu1), p11 = bf_hi(pu1);
    int2 pr = pe[(size_t)d * MAXDEG + lane];
    for (int cb = 0; cb < cnt; cb += 4) {
        float dots[2];
        int sxu[2];
        #pragma unroll
        for (int u = 0; u < 2; u++) {
            int myc = cb + 2 * u + half;
            int cc = myc < cnt ? myc : cnt - 1;
            int sx = __shfl(pr.x, cc);
            int ex = __shfl(pr.y, cc);
            sxu[u] = sx;
            const uint* krow = (const uint*)(qkv16 + (size_t)sx * 384 + 96);
            uint ku0 = krow[l32];
            float e00, e01, e10 = 0.f, e11 = 0.f;
            uint ku1 = 0;
            if (EA16) {
                const uint* er = (const uint*)eaP + (size_t)ex * 48;
                uint eu0 = er[l32]; e00 = bf_lo(eu0); e01 = bf_hi(eu0);
                if (l32 < 16) {
                    uint eu1 = er[32 + l32]; e10 = bf_lo(eu1); e11 = bf_hi(eu1);
                    ku1 = krow[32 + l32];
                }
            } else {
                const float* er = (const float*)eaP + (size_t)ex * DD;
                float2 ef0 = *(const float2*)&er[2 * l32]; e00 = ef0.x; e01 = ef0.y;
                if (l32 < 16) {
                    float2 ef1 = *(const float2*)&er[64 + 2 * l32]; e10 = ef1.x; e11 = ef1.y;
                    ku1 = krow[32 + l32];
                }
            }
            float dot = q00 * bf_lo(ku0) + q01 * bf_hi(ku0)
                      + p00 * e00 + p01 * e01 + p10 * e10 + p11 * e11;
            if (l32 < 16) dot += q10 * bf_lo(ku1) + q11 * bf_hi(ku1);
            dots[u] = dot;
        }
        #pragma unroll
        for (int o = 16; o > 0; o >>= 1) {
            dots[0] += __shfl_xor(dots[0], o);
            dots[1] += __shfl_xor(dots[1], o);
        }
        #pragma unroll
        for (int u = 0; u < 2; u++) {
            int myc = cb + 2 * u + half;
            if (l32 == 0 && myc < cnt) {
                float v = __expf(dots[u] * scale);
                ae_slot[(size_t)d * MAXDEG + myc] = v;
                atomicAdd(&denom[sxu[u]], v);
            }
        }
    }
}

template<bool EA16>
__global__ __launch_bounds__(256)
void edge2w(const ushort* __restrict__ qkv16, const void* __restrict__ eaP,
            const float* __restrict__ ae_slot, const float* __restrict__ denom,
            const int2* __restrict__ pe, const int* __restrict__ deg,
            float* __restrict__ agg, ushort* __restrict__ T16)
{
    int lane = threadIdx.x & 63;
    int half = lane >> 5, l32 = lane & 31;
    int d = blockIdx.x * 4 + (threadIdx.x >> 6);
    if (d >= N_NODES) return;
    int cnt = deg[d]; if (cnt > MAXDEG) cnt = MAXDEG;
    int2 pr = pe[(size_t)d * MAXDEG + lane];
    float ar = ae_slot[(size_t)d * MAXDEG + lane];
    float a00 = 0.f, a01 = 0.f, a10 = 0.f, a11 = 0.f;
    float t00 = 0.f, t01 = 0.f, t10 = 0.f, t11 = 0.f;
    for (int cb = 0; cb < cnt; cb += 4) {
        #pragma unroll
        for (int u = 0; u < 2; u++) {
            int myc = cb + 2 * u + half;
            int cc = myc < cnt ? myc : cnt - 1;
            int sx = __shfl(pr.x, cc);
            int ex = __shfl(pr.y, cc);
            float ae = __shfl(ar, cc);
            float w = (myc < cnt) ? ae / denom[sx] : 0.f;
            const uint* vrow = (const uint*)(qkv16 + (size_t)sx * 384 + 192);
            uint vu0 = vrow[l32];
            float e00, e01, e10 = 0.f, e11 = 0.f;
            uint vu1 = 0;
            if (EA16) {
                const uint* er = (const uint*)eaP + (size_t)ex * 48;
                uint eu0 = er[l32]; e00 = bf_lo(eu0); e01 = bf_hi(eu0);
                if (l32 < 16) {
                    uint eu1 = er[32 + l32]; e10 = bf_lo(eu1); e11 = bf_hi(eu1);
                    vu1 = vrow[32 + l32];
                }
            } else {
                const float* er = (const float*)eaP + (size_t)ex * DD;
                float2 ef0 = *(const float2*)&er[2 * l32]; e00 = ef0.x; e01 = ef0.y;
                if (l32 < 16) {
                    float2 ef1 = *(const float2*)&er[64 + 2 * l32]; e10 = ef1.x; e11 = ef1.y;
                    vu1 = vrow[32 + l32];
                }
            }
            a00 += w * bf_lo(vu0); a01 += w * bf_hi(vu0);
            t00 += w * e00; t01 += w * e01;
            if (l32 < 16) {
                a10 += w * bf_lo(vu1); a11 += w * bf_hi(vu1);
                t10 += w * e10; t11 += w * e11;
            }
        }
    }
    // cross-half combine
    a00 += __shfl_xor(a00, 32); a01 += __shfl_xor(a01, 32);
    a10 += __shfl_xor(a10, 32); a11 += __shfl_xor(a11, 32);
    t00 += __shfl_xor(t00, 32); t01 += __shfl_xor(t01, 32);
    t10 += __shfl_xor(t10, 32); t11 += __shfl_xor(t11, 32);
    if (half == 0) {
        *(float2*)&agg[(size_t)d * DD + 2 * l32] = make_float2(a00, a01);
        ((uint*)T16)[(size_t)d * 48 + l32] = ((uint)f2bf(t01) << 16) | f2bf(t00);
        if (l32 < 16) {
            *(float2*)&agg[(size_t)d * DD + 64 + 2 * l32] = make_float2(a10, a11);
            ((uint*)T16)[(size_t)d * 48 + 32 + l32] = ((uint)f2bf(t11) << 16) | f2bf(t10);
        }
    }
}

// ---------------- LayerNorm: out16 = LN(a16 (+b)) * g + beta ----------------
// BMODE: 0 = no b, 1 = b fp32, 2 = b bf16
template<int RL, int BMODE>
__global__ __launch_bounds__(256)
void ln_b(const ushort* __restrict__ a, const void* __restrict__ bP,
          const float* __restrict__ g, const float* __restrict__ beta,
          ushort* __restrict__ out, int M)
{
    int wave = threadIdx.x >> 6;
    int lane = threadIdx.x & 63;
    int row = blockIdx.x * 4 + wave;
    if (row >= M) return;
    const int NE = (RL + 63) / 64;
    float vals[NE];
    float s = 0.f;
    #pragma unroll
    for (int i = 0; i < NE; i++) {
        int j = lane + i * 64;
        float x = 0.f;
        if (j < RL) {
            x = bfs(a[(size_t)row * RL + j]);
            if (BMODE == 1) x += ((const float*)bP)[(size_t)row * RL + j];
            if (BMODE == 2) x += bfs(((const ushort*)bP)[(size_t)row * RL + j]);
        }
        vals[i] = x; s += x;
    }
    s = wave_reduce_sum(s);
    float mean = s / RL;
    float sq = 0.f;
    #pragma unroll
    for (int i = 0; i < NE; i++) {
        int j = lane + i * 64;
        if (j < RL) { float dd = vals[i] - mean; sq += dd * dd; }
    }
    sq = wave_reduce_sum(sq);
    float rstd = rsqrtf(sq / RL + 1e-5f);
    #pragma unroll
    for (int i = 0; i < NE; i++) {
        int j = lane + i * 64;
        if (j < RL)
            out[(size_t)row * RL + j] = f2bf((vals[i] - mean) * rstd * g[j] + beta[j]);
    }
}

// ---------------- mean-pool: segment-run register accumulation ----------------
// batch_index is SORTED. One block per PCHUNK contiguous nodes; 192 threads,
// thread j owns dim pair (2j, 2j+1) -> one uint (2x bf16) per node, 768 B/node
// coalesced. Accumulate run in registers; flush via atomicAdd only at graph
// boundaries (~1-2 per chunk) instead of per node (was 19.2M atomics).
#define PCHUNK 64
__global__ __launch_bounds__(192)
void pool2_k(const ushort* __restrict__ u, const int* __restrict__ batch,
             float* __restrict__ pooled, float* __restrict__ cnt)
{
    int j = threadIdx.x;                   // 0..191 dim-pair index
    int n0 = blockIdx.x * PCHUNK;
    if (n0 >= N_NODES) return;
    int n1 = n0 + PCHUNK; if (n1 > N_NODES) n1 = N_NODES;
    float a0 = 0.f, a1 = 0.f;
    int cur = batch[n0];
    int runStart = n0;
    for (int n = n0; n < n1; n++) {
        int bg = batch[n];                 // uniform across block
        if (bg != cur) {
            atomicAdd(&pooled[(size_t)cur * HH + 2 * j], a0);
            atomicAdd(&pooled[(size_t)cur * HH + 2 * j + 1], a1);
            if (j == 0) atomicAdd(&cnt[cur], (float)(n - runStart));
            a0 = 0.f; a1 = 0.f; cur = bg; runStart = n;
        }
        uint v = ((const uint*)u)[(size_t)n * 192 + j];
        a0 += bf_lo(v); a1 += bf_hi(v);
    }
    atomicAdd(&pooled[(size_t)cur * HH + 2 * j], a0);
    atomicAdd(&pooled[(size_t)cur * HH + 2 * j + 1], a1);
    if (j == 0) atomicAdd(&cnt[cur], (float)(n1 - runStart));
}

// ---------------- classifier head ----------------
__global__ __launch_bounds__(64)
void clf_k(const float* __restrict__ pooled, const float* __restrict__ cnt,
           const float* __restrict__ W, const float* __restrict__ bcl,
           float* __restrict__ out)
{
    int g = blockIdx.x;
    int lane = threadIdx.x;
    float c = cnt[g]; c = c > 1.f ? c : 1.f;
    float inv = 1.f / c;
    float a0 = 0.f, a1 = 0.f;
    #pragma unroll
    for (int i = 0; i < 6; i++) {
        int j = lane + i * 64;
        float pv = pooled[(size_t)g * HH + j] * inv;
        a0 += pv * W[j * 2 + 0];
        a1 += pv * W[j * 2 + 1];
    }
    a0 = wave_reduce_sum(a0);
    a1 = wave_reduce_sum(a1);
    if (lane == 0) {
        out[g * 2 + 0] = a0 + bcl[0];
        out[g * 2 + 1] = a1 + bcl[1];
    }
}

extern "C" void kernel_launch(void* const* d_in, const int* in_sizes, int n_in,
                              void* d_out, int out_size, void* d_ws, size_t ws_size,
                              hipStream_t stream)
{
    const float* x       = (const float*)d_in[0];
    const float* ea      = (const float*)d_in[1];
    const float* emb_W1  = (const float*)d_in[2];
    const float* emb_b1  = (const float*)d_in[3];
    const float* emb_W2  = (const float*)d_in[4];
    const float* emb_b2  = (const float*)d_in[5];
    const float* Wq      = (const float*)d_in[6];
    const float* Wk      = (const float*)d_in[7];
    const float* Wv      = (const float*)d_in[8];
    const float* ffn_W1  = (const float*)d_in[9];
    const float* ffn_W2  = (const float*)d_in[10];
    const float* bq      = (const float*)d_in[11];
    const float* bk      = (const float*)d_in[12];
    const float* bv      = (const float*)d_in[13];
    const float* ffn_b1  = (const float*)d_in[14];
    const float* ffn_b2  = (const float*)d_in[15];
    const float* n1_b    = (const float*)d_in[16];
    const float* n2_b    = (const float*)d_in[17];
    const float* n1_g    = (const float*)d_in[18];
    const float* n2_g    = (const float*)d_in[19];
    const float* u_W1    = (const float*)d_in[20];
    const float* u_b1    = (const float*)d_in[21];
    const float* u_W2    = (const float*)d_in[22];
    const float* u_b2    = (const float*)d_in[23];
    const float* u_g     = (const float*)d_in[24];
    const float* u_bb    = (const float*)d_in[25];
    const float* clf_W   = (const float*)d_in[26];
    const float* clf_b   = (const float*)d_in[27];
    const float* rec_W1  = (const float*)d_in[28];
    const float* rec_b1  = (const float*)d_in[29];
    const float* rec_W2  = (const float*)d_in[30];
    const float* rec_b2  = (const float*)d_in[31];
    const int* edge_index = (const int*)d_in[32];
    const int* batch     = (const int*)d_in[33];
    const int* srcI = edge_index;
    const int* dstI = edge_index + N_EDGES;

    float* out   = (float*)d_out;
    float* r_out = out + NGRAPH * NOUT_;

    // ---- workspace bump allocator (256B aligned) ----
    char* base = (char*)d_ws;
    size_t off = 0;
    auto alloc = [&](size_t bytes) -> char* {
        char* r = base + off;
        off += (bytes + 255) & ~(size_t)255;
        return r;
    };
    ushort* h16     = (ushort*)alloc((size_t)N_NODES * DD * 2);
    ushort* qkv16   = (ushort*)alloc((size_t)N_NODES * HH * 2);
    float*  agg     = (float*) alloc((size_t)N_NODES * DD * 4);   // agg,T16,h116 contiguous
    ushort* T16     = (ushort*)alloc((size_t)N_NODES * DD * 2);
    ushort* h116    = (ushort*)alloc((size_t)N_NODES * DD * 2);
    int2*   pe      = (int2*)  alloc((size_t)N_NODES * MAXDEG * 8); // pe,ae_slot contiguous
    float*  ae_slot = (float*) alloc((size_t)N_NODES * MAXDEG * 4);
    ushort* f116    = (ushort*)alloc((size_t)N_NODES * DD * 2);
    float*  denom   = (float*) alloc((size_t)N_NODES * 4);
    int*    deg     = (int*)   alloc((size_t)N_NODES * 4);
    float*  pooled  = (float*) alloc((size_t)NGRAPH * HH * 4);
    float*  cnt     = (float*) alloc(NGRAPH * 4);
    float*  Wcat    = (float*) alloc((size_t)NLAYERS * DD * 4 * DD * 4);
    float*  bcat    = (float*) alloc((size_t)NLAYERS * 4 * DD * 4);
    ushort* x16     = (ushort*)alloc((size_t)N_NODES * INF_ * 2);
    ushort* embW1T  = (ushort*)alloc((size_t)HH * INF_ * 2);
    ushort* embW2T  = (ushort*)alloc((size_t)DD * HH * 2);
    ushort* WcatT   = (ushort*)alloc((size_t)NLAYERS * HH * DD * 2);
    ushort* WvT     = (ushort*)alloc((size_t)NLAYERS * DD * DD * 2);
    ushort* fW1T    = (ushort*)alloc((size_t)NLAYERS * DD * DD * 2);
    ushort* fW2T    = (ushort*)alloc((size_t)NLAYERS * DD * DD * 2);
    ushort* uW1T    = (ushort*)alloc((size_t)HH * DD * 2);
    ushort* uW2T    = (ushort*)alloc((size_t)HH * HH * 2);
    ushort* recW1T  = (ushort*)alloc((size_t)HH * HH * 2);
    ushort* recW2T  = (ushort*)alloc((size_t)INF_ * HH * 2);
    ushort* ea16 = (ushort*)alloc((size_t)N_EDGES * DD * 2);
    bool use_ea16 = (ws_size >= off);
    const void* eaP = use_ea16 ? (const void*)ea16 : (const void*)ea;

    // head-phase aliases (layer buffers dead)
    ushort* t16    = qkv16;                 // 38.4 MB
    ushort* upre16 = (ushort*)agg;          // spans agg+T16+h116 = 38.4 MB
    ushort* u16    = (ushort*)pe;           // spans pe+ae_slot = 38.4 MB
    ushort* rtmp16 = qkv16;                 // t16 dead after u2

    dim3 blk(256);
    const int GB = (N_NODES + 127) / 128;   // 391
    const float scale = 1.f / sqrtf((float)DD);

    // ---- weight precompute/pack ----
    wqk_k<<<dim3(36, NLAYERS), blk, 0, stream>>>(Wq, Wk, bq, Wcat, bcat);
    pack_k<<<(NLAYERS * DD * 288 + 255) / 256, blk, 0, stream>>>(
        Wq, Wk, Wv, bq, bk, bv, Wcat, bcat);
    PackArgs pa;
    int pi = 0;
    auto addp = [&](const float* s, ushort* d, int K, int N) {
        pa.src[pi] = s; pa.dst[pi] = d; pa.K[pi] = K; pa.N[pi] = N; pi++;
    };
    addp(emb_W1, embW1T, INF_, HH);
    addp(emb_W2, embW2T, HH, DD);
    for (int l = 0; l < NLAYERS; l++) addp(Wcat + (size_t)l * DD * 4 * DD, WcatT + (size_t)l * HH * DD, DD, HH);
    for (int l = 0; l < NLAYERS; l++) addp(Wv + (size_t)l * DD * DD, WvT + (size_t)l * DD * DD, DD, DD);
    for (int l = 0; l < NLAYERS; l++) addp(ffn_W1 + (size_t)l * DD * DD, fW1T + (size_t)l * DD * DD, DD, DD);
    for (int l = 0; l < NLAYERS; l++) addp(ffn_W2 + (size_t)l * DD * DD, fW2T + (size_t)l * DD * DD, DD, DD);
    addp(u_W1, uW1T, DD, HH);
    addp(u_W2, uW2T, HH, HH);
    addp(rec_W1, recW1T, HH, HH);
    addp(rec_W2, recW2T, HH, INF_);
    packT_k<<<dim3(576, NPACK), blk, 0, stream>>>(pa);

    // ---- input converts ----
    cvt16<<<((size_t)N_NODES * INF_ / 4 + 255) / 256, blk, 0, stream>>>(
        x, x16, (long)N_NODES * INF_);
    if (use_ea16)
        cvt16<<<((size_t)N_EDGES * DD / 4 + 255) / 256, blk, 0, stream>>>(
            ea, ea16, (long)N_EDGES * DD);

    // ---- atom embedding MLP ----
    gemm_mf<128, ACT_RELU, false, true><<<dim3(GB, 3), blk, 0, stream>>>(
        x16, embW1T, emb_b1, nullptr, t16, N_NODES, HH, INF_);
    gemm_mf<96, ACT_NONE, false, true><<<dim3(GB, 1), blk, 0, stream>>>(
        t16, embW2T, emb_b2, nullptr, h16, N_NODES, DD, HH);

    // ---- adjacency build ----
    hipMemsetAsync(deg, 0, N_NODES * sizeof(int), stream);
    scatter_k<<<(N_EDGES + 255) / 256, blk, 0, stream>>>(srcI, dstI, deg, pe);

    // ---- RPETConv layers ----
    const int EGRID = (N_NODES + 3) / 4;
    for (int l = 0; l < NLAYERS; l++) {
        gemm_mf<128, ACT_NONE, false, true><<<dim3(GB, 3), blk, 0, stream>>>(
            h16, WcatT + (size_t)l * HH * DD, bcat + (size_t)l * 4 * DD,
            nullptr, qkv16, N_NODES, HH, DD);

        hipMemsetAsync(denom, 0, N_NODES * sizeof(float), stream);
        if (use_ea16) {
            edge1w<true><<<EGRID, blk, 0, stream>>>(
                qkv16, eaP, pe, deg, ae_slot, denom, scale);
            edge2w<true><<<EGRID, blk, 0, stream>>>(
                qkv16, eaP, ae_slot, denom, pe, deg, agg, T16);
        } else {
            edge1w<false><<<EGRID, blk, 0, stream>>>(
                qkv16, eaP, pe, deg, ae_slot, denom, scale);
            edge2w<false><<<EGRID, blk, 0, stream>>>(
                qkv16, eaP, ae_slot, denom, pe, deg, agg, T16);
        }

        // agg += T @ Wv
        gemm_mf<96, ACT_NONE, true, false><<<dim3(GB, 1), blk, 0, stream>>>(
            T16, WvT + (size_t)l * DD * DD, nullptr, agg, nullptr, N_NODES, DD, DD);

        ln_b<DD, 1><<<(N_NODES + 3) / 4, blk, 0, stream>>>(
            h16, agg, n1_g + (size_t)l * DD, n1_b + (size_t)l * DD, h116, N_NODES);

        gemm_mf<96, ACT_ELU, false, true><<<dim3(GB, 1), blk, 0, stream>>>(
            h116, fW1T + (size_t)l * DD * DD, ffn_b1 + (size_t)l * DD,
            nullptr, f116, N_NODES, DD, DD);
        gemm_mf<96, ACT_NONE, false, true><<<dim3(GB, 1), blk, 0, stream>>>(
            f116, fW2T + (size_t)l * DD * DD, ffn_b2 + (size_t)l * DD,
            nullptr, T16, N_NODES, DD, DD);   // T16 dead -> reuse as f2 buffer
        ln_b<DD, 2><<<(N_NODES + 3) / 4, blk, 0, stream>>>(
            T16, h116, n2_g + (size_t)l * DD, n2_b + (size_t)l * DD, h16, N_NODES);
    }

    // ---- updim + LN ----
    gemm_mf<128, ACT_LEAKY, false, true><<<dim3(GB, 3), blk, 0, stream>>>(
        h16, uW1T, u_b1, nullptr, t16, N_NODES, HH, DD);
    gemm_mf<128, ACT_NONE, false, true><<<dim3(GB, 3), blk, 0, stream>>>(
        t16, uW2T, u_b2, nullptr, upre16, N_NODES, HH, HH);
    ln_b<HH, 0><<<(N_NODES + 3) / 4, blk, 0, stream>>>(
        upre16, nullptr, u_g, u_bb, u16, N_NODES);

    // ---- mean pool + classifier ----
    hipMemsetAsync(pooled, 0, (size_t)(NGRAPH * HH + NGRAPH) * sizeof(float), stream);
    pool2_k<<<(N_NODES + PCHUNK - 1) / PCHUNK, 192, 0, stream>>>(u16, batch, pooled, cnt);
    clf_k<<<NGRAPH, 64, 0, stream>>>(pooled, cnt, clf_W, clf_b, out);

    // ---- reconstruction head ----
    gemm_mf<128, ACT_RELU, false, true><<<dim3(GB, 3), blk, 0, stream>>>(
        u16, recW1T, rec_b1, nullptr, rtmp16, N_NODES, HH, HH);
    gemm_mf<64, ACT_NONE, false, false><<<dim3(GB, 1), blk, 0, stream>>>(
        rtmp16, recW2T, rec_b2, r_out, nullptr, N_NODES, INF_, HH);
}

// Round 2
// 1556.378 us; speedup vs baseline: 1.1417x; 1.0675x over previous
//
#include <hip/hip_runtime.h>
#include <math.h>

#define N_NODES 50000
#define N_EDGES 640000
#define INF_ 64
#define DD 96
#define HH 384
#define NLAYERS 4
#define NGRAPH 512
#define NOUT_ 2
#define MAXDEG 64

#define ACT_NONE 0
#define ACT_RELU 1
#define ACT_ELU 2
#define ACT_LEAKY 3

typedef unsigned int uint;
typedef unsigned short ushort;
typedef __attribute__((ext_vector_type(8))) short v8s;   // 8 bf16 (4 VGPRs)
typedef __attribute__((ext_vector_type(4))) float v4f;   // 4 fp32 acc

__device__ __forceinline__ float bf_lo(uint u) { return __uint_as_float(u << 16); }
__device__ __forceinline__ float bf_hi(uint u) { return __uint_as_float(u & 0xffff0000u); }
__device__ __forceinline__ float bfs(ushort s) { return __uint_as_float(((uint)s) << 16); }
__device__ __forceinline__ ushort f2bf(float f)
{
    uint u = __float_as_uint(f);
    return (ushort)((u + 0x7fffu + ((u >> 16) & 1u)) >> 16);
}

// ================= MFMA bf16 GEMM: C = act(A@B (+bias) (+C)) =================
// A: M x K bf16 row-major. Bt: N x K bf16 row-major (pre-transposed weights).
// BM=128, 256 thr = 4 waves (2x2), wave tile 64 x BN/2. K % 32 == 0, Nc % BN == 0.
template<int BN, int ACT, bool ACCUM, bool OUT16>
__global__ __launch_bounds__(256)
void gemm_mf(const ushort* __restrict__ A, const ushort* __restrict__ Bt,
             const float* __restrict__ bias, float* __restrict__ C32,
             ushort* __restrict__ C16, int M, int Nc, int K)
{
    const int BM = 128, LDA = 40;      // 32 + 8 pad (bf16 units) -> 2-way b128, free
    const int FN = BN / 32;            // n-fragments per wave
    __shared__ ushort As[BM * LDA];
    __shared__ ushort Bs[BN * LDA];
    int tid = threadIdx.x;
    int lane = tid & 63, wave = tid >> 6;
    int ln15 = lane & 15, quad = lane >> 4;
    int wm = (wave >> 1) * 64, wn = (wave & 1) * (BN / 2);
    int bm0 = blockIdx.x * BM, bn0 = blockIdx.y * BN;

    v4f acc[4][FN];
    #pragma unroll
    for (int i = 0; i < 4; i++)
        #pragma unroll
        for (int j = 0; j < FN; j++) acc[i][j] = (v4f){0.f, 0.f, 0.f, 0.f};

    for (int k0 = 0; k0 < K; k0 += 32) {
        #pragma unroll
        for (int it = 0; it < 2; it++) {
            int u = it * 256 + tid;
            int r = u >> 2, c8 = (u & 3) * 8;
            int row = bm0 + r;
            int4 v = make_int4(0, 0, 0, 0);
            if (row < M) v = *(const int4*)&A[(size_t)row * K + k0 + c8];
            *(int4*)&As[r * LDA + c8] = v;
        }
        #pragma unroll
        for (int it = 0; it < (BN * 4 + 255) / 256; it++) {
            int u = it * 256 + tid;
            if ((BN * 4) % 256 == 0 || u < BN * 4) {
                int r = u >> 2, c8 = (u & 3) * 8;
                *(int4*)&Bs[r * LDA + c8] =
                    *(const int4*)&Bt[(size_t)(bn0 + r) * K + k0 + c8];
            }
        }
        __syncthreads();
        v8s af[4], bf[FN];
        #pragma unroll
        for (int i = 0; i < 4; i++)
            af[i] = *(const v8s*)&As[(wm + i * 16 + ln15) * LDA + quad * 8];
        #pragma unroll
        for (int j = 0; j < FN; j++)
            bf[j] = *(const v8s*)&Bs[(wn + j * 16 + ln15) * LDA + quad * 8];
        #pragma unroll
        for (int i = 0; i < 4; i++)
            #pragma unroll
            for (int j = 0; j < FN; j++)
                acc[i][j] = __builtin_amdgcn_mfma_f32_16x16x32_bf16(
                    af[i], bf[j], acc[i][j], 0, 0, 0);
        __syncthreads();
    }
    #pragma unroll
    for (int i = 0; i < 4; i++) {
        #pragma unroll
        for (int j = 0; j < FN; j++) {
            int col = bn0 + wn + j * 16 + ln15;
            float bsv = bias ? bias[col] : 0.f;
            #pragma unroll
            for (int r = 0; r < 4; r++) {
                int row = bm0 + wm + i * 16 + quad * 4 + r;
                if (row >= M) continue;
                float v = acc[i][j][r] + bsv;
                if (ACCUM) v += C32[(size_t)row * Nc + col];
                if (ACT == ACT_RELU)       v = fmaxf(v, 0.f);
                else if (ACT == ACT_ELU)   v = v > 0.f ? v : expm1f(v);
                else if (ACT == ACT_LEAKY) v = v > 0.f ? v : 0.01f * v;
                if (OUT16) C16[(size_t)row * Nc + col] = f2bf(v);
                else       C32[(size_t)row * Nc + col] = v;
            }
        }
    }
}

// ============ MFMA GEMM (BN=96, full row per block) + fused LayerNorm ============
// out16 = LN( A@Bt (+bias) (+C32) + add16 ) * g + beta       (row width fixed = 96)
template<bool ACC32>
__global__ __launch_bounds__(256)
void gemm_ln(const ushort* __restrict__ A, const ushort* __restrict__ Bt,
             const float* __restrict__ bias, const float* __restrict__ C32,
             const ushort* __restrict__ add16,
             const float* __restrict__ g, const float* __restrict__ beta,
             ushort* __restrict__ out, int M, int K)
{
    const int BM = 128, LDA = 40, FN = 3;   // BN = 96
    __shared__ ushort As[BM * LDA];
    __shared__ ushort Bs[96 * LDA];
    __shared__ float2 red[2][2][64];        // [rowhalf][colhalf][row]
    int tid = threadIdx.x;
    int lane = tid & 63, wave = tid >> 6;
    int ln15 = lane & 15, quad = lane >> 4;
    int wm = (wave >> 1) * 64, wn = (wave & 1) * 48;
    int bm0 = blockIdx.x * BM;

    v4f acc[4][FN];
    #pragma unroll
    for (int i = 0; i < 4; i++)
        #pragma unroll
        for (int j = 0; j < FN; j++) acc[i][j] = (v4f){0.f, 0.f, 0.f, 0.f};

    for (int k0 = 0; k0 < K; k0 += 32) {
        #pragma unroll
        for (int it = 0; it < 2; it++) {
            int u = it * 256 + tid;
            int r = u >> 2, c8 = (u & 3) * 8;
            int row = bm0 + r;
            int4 v = make_int4(0, 0, 0, 0);
            if (row < M) v = *(const int4*)&A[(size_t)row * K + k0 + c8];
            *(int4*)&As[r * LDA + c8] = v;
        }
        #pragma unroll
        for (int it = 0; it < 2; it++) {
            int u = it * 256 + tid;
            if (u < 384) {
                int r = u >> 2, c8 = (u & 3) * 8;
                *(int4*)&Bs[r * LDA + c8] =
                    *(const int4*)&Bt[(size_t)r * K + k0 + c8];
            }
        }
        __syncthreads();
        v8s af[4], bf[FN];
        #pragma unroll
        for (int i = 0; i < 4; i++)
            af[i] = *(const v8s*)&As[(wm + i * 16 + ln15) * LDA + quad * 8];
        #pragma unroll
        for (int j = 0; j < FN; j++)
            bf[j] = *(const v8s*)&Bs[(wn + j * 16 + ln15) * LDA + quad * 8];
        #pragma unroll
        for (int i = 0; i < 4; i++)
            #pragma unroll
            for (int j = 0; j < FN; j++)
                acc[i][j] = __builtin_amdgcn_mfma_f32_16x16x32_bf16(
                    af[i], bf[j], acc[i][j], 0, 0, 0);
        __syncthreads();
    }

    // epilogue: v = acc + bias + C32? + add16; row stats; LN; store
    float s1a[4][4], s2a[4][4];
    #pragma unroll
    for (int i = 0; i < 4; i++)
        #pragma unroll
        for (int r = 0; r < 4; r++) { s1a[i][r] = 0.f; s2a[i][r] = 0.f; }

    #pragma unroll
    for (int i = 0; i < 4; i++) {
        #pragma unroll
        for (int j = 0; j < FN; j++) {
            int col = wn + j * 16 + ln15;
            float bsv = bias ? bias[col] : 0.f;
            #pragma unroll
            for (int r = 0; r < 4; r++) {
                int row = bm0 + wm + i * 16 + quad * 4 + r;
                float v = acc[i][j][r] + bsv;
                if (row < M) {
                    if (ACC32) v += C32[(size_t)row * DD + col];
                    v += bfs(add16[(size_t)row * DD + col]);
                }
                acc[i][j][r] = v;
                s1a[i][r] += v; s2a[i][r] += v * v;
            }
        }
    }
    #pragma unroll
    for (int o = 1; o <= 8; o <<= 1) {
        #pragma unroll
        for (int i = 0; i < 4; i++)
            #pragma unroll
            for (int r = 0; r < 4; r++) {
                s1a[i][r] += __shfl_xor(s1a[i][r], o);
                s2a[i][r] += __shfl_xor(s2a[i][r], o);
            }
    }
    if (ln15 == 0) {
        #pragma unroll
        for (int i = 0; i < 4; i++)
            #pragma unroll
            for (int r = 0; r < 4; r++)
                red[wave >> 1][wave & 1][i * 16 + quad * 4 + r] =
                    make_float2(s1a[i][r], s2a[i][r]);
    }
    __syncthreads();
    float gj[FN], bj[FN];
    #pragma unroll
    for (int j = 0; j < FN; j++) {
        gj[j] = g[wn + j * 16 + ln15];
        bj[j] = beta[wn + j * 16 + ln15];
    }
    #pragma unroll
    for (int i = 0; i < 4; i++) {
        #pragma unroll
        for (int r = 0; r < 4; r++) {
            int row = bm0 + wm + i * 16 + quad * 4 + r;
            if (row >= M) continue;
            float2 o = red[wave >> 1][(wave & 1) ^ 1][i * 16 + quad * 4 + r];
            float tot1 = s1a[i][r] + o.x;
            float tot2 = s2a[i][r] + o.y;
            float mean = tot1 * (1.f / 96.f);
            float var  = tot2 * (1.f / 96.f) - mean * mean;
            float rstd = rsqrtf(var + 1e-5f);
            #pragma unroll
            for (int j = 0; j < FN; j++) {
                int col = wn + j * 16 + ln15;
                out[(size_t)row * DD + col] =
                    f2bf((acc[i][j][r] - mean) * rstd * gj[j] + bj[j]);
            }
        }
    }
}

__device__ __forceinline__ float wave_reduce_sum(float v)
{
    #pragma unroll
    for (int o = 32; o > 0; o >>= 1) v += __shfl_xor(v, o, 64);
    return v;
}

// ---------------- fp32 -> bf16 convert ----------------
__global__ __launch_bounds__(256)
void cvt16(const float* __restrict__ in, ushort* __restrict__ out, long n)
{
    long i = ((long)blockIdx.x * 256 + threadIdx.x) * 4;
    if (i >= n) return;
    float4 v = *(const float4*)&in[i];
    ushort4 o;
    o.x = f2bf(v.x); o.y = f2bf(v.y); o.z = f2bf(v.z); o.w = f2bf(v.w);
    *(ushort4*)&out[i] = o;
}

// ---------------- Wqk = Wq@Wk^T, bqk = bq@Wk^T -> Wcat cols 288..383 (fp32) ----------
__global__ __launch_bounds__(256)
void wqk_k(const float* __restrict__ Wq, const float* __restrict__ Wk,
           const float* __restrict__ bq, float* __restrict__ Wcat, float* __restrict__ bcat)
{
    int l = blockIdx.y;
    int idx = blockIdx.x * 256 + threadIdx.x;
    const float* wq = Wq + (size_t)l * DD * DD;
    const float* wk = Wk + (size_t)l * DD * DD;
    if (idx < DD * DD) {
        int k = idx / DD, j = idx % DD;
        float s = 0.f;
        for (int t = 0; t < DD; t++) s += wq[k * DD + t] * wk[j * DD + t];
        Wcat[(size_t)l * DD * 4 * DD + (size_t)k * 4 * DD + 288 + j] = s;
    }
    if (idx < DD) {
        int j = idx;
        float s = 0.f;
        for (int t = 0; t < DD; t++) s += bq[l * DD + t] * wk[j * DD + t];
        bcat[l * 4 * DD + 288 + j] = s;
    }
}

// ---------------- pack [Wq|Wk|Wv] into Wcat cols 0..287 + biases (fp32) ----------------
__global__ __launch_bounds__(256)
void pack_k(const float* __restrict__ Wq, const float* __restrict__ Wk,
            const float* __restrict__ Wv, const float* __restrict__ bq,
            const float* __restrict__ bk, const float* __restrict__ bv,
            float* __restrict__ Wcat, float* __restrict__ bcat)
{
    int idx = blockIdx.x * 256 + threadIdx.x;
    if (idx >= NLAYERS * DD * 288) return;
    int l = idx / (DD * 288);
    int rem = idx % (DD * 288);
    int k = rem / 288, n = rem % 288;
    int which = n / DD, j = n % DD;
    const float* W = which == 0 ? Wq : (which == 1 ? Wk : Wv);
    Wcat[(size_t)l * DD * 4 * DD + (size_t)k * 4 * DD + n] =
        W[(size_t)l * DD * DD + k * DD + j];
    if (k == 0) {
        const float* bb = which == 0 ? bq : (which == 1 ? bk : bv);
        bcat[l * 4 * DD + n] = bb[l * DD + j];
    }
}

// ---------------- transpose+convert all weights: src KxN fp32 -> dst NxK bf16 ----------
#define NPACK 22
struct PackArgs {
    const float* src[NPACK];
    ushort* dst[NPACK];
    int K[NPACK], N[NPACK];
};
__global__ __launch_bounds__(256)
void packT_k(PackArgs pa)
{
    int w = blockIdx.y;
    int K = pa.K[w], N = pa.N[w];
    int idx = blockIdx.x * 256 + threadIdx.x;
    if (idx >= K * N) return;
    int n = idx / K, k = idx % K;           // write-coalesced
    pa.dst[w][(size_t)n * K + k] = f2bf(pa.src[w][(size_t)k * N + n]);
}

// ---------------- adjacency build (padded slots) ----------------
__global__ __launch_bounds__(256)
void scatter_k(const int* __restrict__ src, const int* __restrict__ dst,
               int* __restrict__ deg, int2* __restrict__ pe)
{
    int e = blockIdx.x * 256 + threadIdx.x;
    if (e >= N_EDGES) return;
    int d = dst[e];
    int c = atomicAdd(&deg[d], 1);
    if (c < MAXDEG) pe[(size_t)d * MAXDEG + c] = make_int2(src[e], e);
}

// qkv16 row layout (uint units, stride 192): [0:48)=Q [48:96)=K [96:144)=V [144:192)=Qk
// One 64-lane wave per dst node; 4x 16-lane groups each own one edge; D=96 = 3 uints
// per lane over 16 lanes (perfectly balanced, no divergence). Unroll x2 -> 8 edges
// in flight per wave; dot reduce = 4 shfl steps within the group.
template<bool EA16>
__global__ __launch_bounds__(256)
void edge1w(const ushort* __restrict__ qkv16, const void* __restrict__ eaP,
            const int2* __restrict__ pe, const int* __restrict__ deg,
            float* __restrict__ ae_slot, float* __restrict__ denom, float scale)
{
    int lane = threadIdx.x & 63;
    int grp = lane >> 4, t = lane & 15;
    int d = blockIdx.x * 4 + (threadIdx.x >> 6);
    if (d >= N_NODES) return;
    int cnt = deg[d]; if (cnt > MAXDEG) cnt = MAXDEG;
    if (cnt == 0) return;
    const uint* row = (const uint*)qkv16 + (size_t)d * 192;
    uint qa = row[t], qb = row[16 + t], qc = row[32 + t];
    uint pa = row[144 + t], pb = row[160 + t], pc = row[176 + t];
    float q0l = bf_lo(qa), q0h = bf_hi(qa), q1l = bf_lo(qb), q1h = bf_hi(qb),
          q2l = bf_lo(qc), q2h = bf_hi(qc);
    float p0l = bf_lo(pa), p0h = bf_hi(pa), p1l = bf_lo(pb), p1h = bf_hi(pb),
          p2l = bf_lo(pc), p2h = bf_hi(pc);
    int2 pr = pe[(size_t)d * MAXDEG + lane];
    for (int cb = 0; cb < cnt; cb += 8) {
        float dots[2];
        int sxu[2];
        #pragma unroll
        for (int u = 0; u < 2; u++) {
            int myc = cb + u * 4 + grp;
            int cc = myc < cnt ? myc : cnt - 1;
            int sx = __shfl(pr.x, cc);
            int ex = __shfl(pr.y, cc);
            sxu[u] = sx;
            const uint* kr = (const uint*)qkv16 + (size_t)sx * 192 + 48;
            uint k0 = kr[t], k1 = kr[16 + t], k2 = kr[32 + t];
            float e0l, e0h, e1l, e1h, e2l, e2h;
            if (EA16) {
                const uint* er = (const uint*)eaP + (size_t)ex * 48;
                uint e0 = er[t], e1 = er[16 + t], e2 = er[32 + t];
                e0l = bf_lo(e0); e0h = bf_hi(e0);
                e1l = bf_lo(e1); e1h = bf_hi(e1);
                e2l = bf_lo(e2); e2h = bf_hi(e2);
            } else {
                const float* er = (const float*)eaP + (size_t)ex * DD;
                float2 f0 = *(const float2*)&er[2 * t];
                float2 f1 = *(const float2*)&er[32 + 2 * t];
                float2 f2 = *(const float2*)&er[64 + 2 * t];
                e0l = f0.x; e0h = f0.y; e1l = f1.x; e1h = f1.y;
                e2l = f2.x; e2h = f2.y;
            }
            dots[u] = q0l * bf_lo(k0) + q0h * bf_hi(k0)
                    + q1l * bf_lo(k1) + q1h * bf_hi(k1)
                    + q2l * bf_lo(k2) + q2h * bf_hi(k2)
                    + p0l * e0l + p0h * e0h + p1l * e1l + p1h * e1h
                    + p2l * e2l + p2h * e2h;
        }
        #pragma unroll
        for (int o = 8; o > 0; o >>= 1) {
            dots[0] += __shfl_xor(dots[0], o);
            dots[1] += __shfl_xor(dots[1], o);
        }
        #pragma unroll
        for (int u = 0; u < 2; u++) {
            int myc = cb + u * 4 + grp;
            if (t == 0 && myc < cnt) {
                float v = __expf(dots[u] * scale);
                ae_slot[(size_t)d * MAXDEG + myc] = v;
                atomicAdd(&denom[sxu[u]], v);
            }
        }
    }
}

template<bool EA16>
__global__ __launch_bounds__(256)
void edge2w(const ushort* __restrict__ qkv16, const void* __restrict__ eaP,
            const float* __restrict__ ae_slot, const float* __restrict__ denom,
            const int2* __restrict__ pe, const int* __restrict__ deg,
            float* __restrict__ agg, ushort* __restrict__ T16)
{
    int lane = threadIdx.x & 63;
    int grp = lane >> 4, t = lane & 15;
    int d = blockIdx.x * 4 + (threadIdx.x >> 6);
    if (d >= N_NODES) return;
    int cnt = deg[d]; if (cnt > MAXDEG) cnt = MAXDEG;
    int2 pr = pe[(size_t)d * MAXDEG + lane];
    float ar = ae_slot[(size_t)d * MAXDEG + lane];
    float a0l = 0.f, a0h = 0.f, a1l = 0.f, a1h = 0.f, a2l = 0.f, a2h = 0.f;
    float t0l = 0.f, t0h = 0.f, t1l = 0.f, t1h = 0.f, t2l = 0.f, t2h = 0.f;
    for (int cb = 0; cb < cnt; cb += 8) {
        #pragma unroll
        for (int u = 0; u < 2; u++) {
            int myc = cb + u * 4 + grp;
            int cc = myc < cnt ? myc : cnt - 1;
            int sx = __shfl(pr.x, cc);
            int ex = __shfl(pr.y, cc);
            float ae = __shfl(ar, cc);
            float w = (myc < cnt) ? ae / denom[sx] : 0.f;
            const uint* vr = (const uint*)qkv16 + (size_t)sx * 192 + 96;
            uint v0 = vr[t], v1 = vr[16 + t], v2 = vr[32 + t];
            float e0l, e0h, e1l, e1h, e2l, e2h;
            if (EA16) {
                const uint* er = (const uint*)eaP + (size_t)ex * 48;
                uint e0 = er[t], e1 = er[16 + t], e2 = er[32 + t];
                e0l = bf_lo(e0); e0h = bf_hi(e0);
                e1l = bf_lo(e1); e1h = bf_hi(e1);
                e2l = bf_lo(e2); e2h = bf_hi(e2);
            } else {
                const float* er = (const float*)eaP + (size_t)ex * DD;
                float2 f0 = *(const float2*)&er[2 * t];
                float2 f1 = *(const float2*)&er[32 + 2 * t];
                float2 f2 = *(const float2*)&er[64 + 2 * t];
                e0l = f0.x; e0h = f0.y; e1l = f1.x; e1h = f1.y;
                e2l = f2.x; e2h = f2.y;
            }
            a0l += w * bf_lo(v0); a0h += w * bf_hi(v0);
            a1l += w * bf_lo(v1); a1h += w * bf_hi(v1);
            a2l += w * bf_lo(v2); a2h += w * bf_hi(v2);
            t0l += w * e0l; t0h += w * e0h;
            t1l += w * e1l; t1h += w * e1h;
            t2l += w * e2l; t2h += w * e2h;
        }
    }
    // cross-group combine (masks 16, 32)
    #pragma unroll
    for (int o = 16; o <= 32; o <<= 1) {
        a0l += __shfl_xor(a0l, o); a0h += __shfl_xor(a0h, o);
        a1l += __shfl_xor(a1l, o); a1h += __shfl_xor(a1h, o);
        a2l += __shfl_xor(a2l, o); a2h += __shfl_xor(a2h, o);
        t0l += __shfl_xor(t0l, o); t0h += __shfl_xor(t0h, o);
        t1l += __shfl_xor(t1l, o); t1h += __shfl_xor(t1h, o);
        t2l += __shfl_xor(t2l, o); t2h += __shfl_xor(t2h, o);
    }
    if (grp == 0) {
        *(float2*)&agg[(size_t)d * DD + 2 * t]      = make_float2(a0l, a0h);
        *(float2*)&agg[(size_t)d * DD + 32 + 2 * t] = make_float2(a1l, a1h);
        *(float2*)&agg[(size_t)d * DD + 64 + 2 * t] = make_float2(a2l, a2h);
        uint* Tw = (uint*)T16 + (size_t)d * 48;
        Tw[t]      = ((uint)f2bf(t0h) << 16) | f2bf(t0l);
        Tw[16 + t] = ((uint)f2bf(t1h) << 16) | f2bf(t1l);
        Tw[32 + t] = ((uint)f2bf(t2h) << 16) | f2bf(t2l);
    }
}

// ---------------- LayerNorm: out16 = LN(a16 (+b)) * g + beta ----------------
// BMODE: 0 = no b, 1 = b fp32, 2 = b bf16
template<int RL, int BMODE>
__global__ __launch_bounds__(256)
void ln_b(const ushort* __restrict__ a, const void* __restrict__ bP,
          const float* __restrict__ g, const float* __restrict__ beta,
          ushort* __restrict__ out, int M)
{
    int wave = threadIdx.x >> 6;
    int lane = threadIdx.x & 63;
    int row = blockIdx.x * 4 + wave;
    if (row >= M) return;
    const int NE = (RL + 63) / 64;
    float vals[NE];
    float s = 0.f;
    #pragma unroll
    for (int i = 0; i < NE; i++) {
        int j = lane + i * 64;
        float x = 0.f;
        if (j < RL) {
            x = bfs(a[(size_t)row * RL + j]);
            if (BMODE == 1) x += ((const float*)bP)[(size_t)row * RL + j];
            if (BMODE == 2) x += bfs(((const ushort*)bP)[(size_t)row * RL + j]);
        }
        vals[i] = x; s += x;
    }
    s = wave_reduce_sum(s);
    float mean = s / RL;
    float sq = 0.f;
    #pragma unroll
    for (int i = 0; i < NE; i++) {
        int j = lane + i * 64;
        if (j < RL) { float dd = vals[i] - mean; sq += dd * dd; }
    }
    sq = wave_reduce_sum(sq);
    float rstd = rsqrtf(sq / RL + 1e-5f);
    #pragma unroll
    for (int i = 0; i < NE; i++) {
        int j = lane + i * 64;
        if (j < RL)
            out[(size_t)row * RL + j] = f2bf((vals[i] - mean) * rstd * g[j] + beta[j]);
    }
}

// ---------------- mean-pool: segment-run register accumulation ----------------
#define PCHUNK 64
__global__ __launch_bounds__(192)
void pool2_k(const ushort* __restrict__ u, const int* __restrict__ batch,
             float* __restrict__ pooled, float* __restrict__ cnt)
{
    int j = threadIdx.x;                   // 0..191 dim-pair index
    int n0 = blockIdx.x * PCHUNK;
    if (n0 >= N_NODES) return;
    int n1 = n0 + PCHUNK; if (n1 > N_NODES) n1 = N_NODES;
    float a0 = 0.f, a1 = 0.f;
    int cur = batch[n0];
    int runStart = n0;
    for (int n = n0; n < n1; n++) {
        int bg = batch[n];                 // uniform across block
        if (bg != cur) {
            atomicAdd(&pooled[(size_t)cur * HH + 2 * j], a0);
            atomicAdd(&pooled[(size_t)cur * HH + 2 * j + 1], a1);
            if (j == 0) atomicAdd(&cnt[cur], (float)(n - runStart));
            a0 = 0.f; a1 = 0.f; cur = bg; runStart = n;
        }
        uint v = ((const uint*)u)[(size_t)n * 192 + j];
        a0 += bf_lo(v); a1 += bf_hi(v);
    }
    atomicAdd(&pooled[(size_t)cur * HH + 2 * j], a0);
    atomicAdd(&pooled[(size_t)cur * HH + 2 * j + 1], a1);
    if (j == 0) atomicAdd(&cnt[cur], (float)(n1 - runStart));
}

// ---------------- classifier head ----------------
__global__ __launch_bounds__(64)
void clf_k(const float* __restrict__ pooled, const float* __restrict__ cnt,
           const float* __restrict__ W, const float* __restrict__ bcl,
           float* __restrict__ out)
{
    int g = blockIdx.x;
    int lane = threadIdx.x;
    float c = cnt[g]; c = c > 1.f ? c : 1.f;
    float inv = 1.f / c;
    float a0 = 0.f, a1 = 0.f;
    #pragma unroll
    for (int i = 0; i < 6; i++) {
        int j = lane + i * 64;
        float pv = pooled[(size_t)g * HH + j] * inv;
        a0 += pv * W[j * 2 + 0];
        a1 += pv * W[j * 2 + 1];
    }
    a0 = wave_reduce_sum(a0);
    a1 = wave_reduce_sum(a1);
    if (lane == 0) {
        out[g * 2 + 0] = a0 + bcl[0];
        out[g * 2 + 1] = a1 + bcl[1];
    }
}

extern "C" void kernel_launch(void* const* d_in, const int* in_sizes, int n_in,
                              void* d_out, int out_size, void* d_ws, size_t ws_size,
                              hipStream_t stream)
{
    const float* x       = (const float*)d_in[0];
    const float* ea      = (const float*)d_in[1];
    const float* emb_W1  = (const float*)d_in[2];
    const float* emb_b1  = (const float*)d_in[3];
    const float* emb_W2  = (const float*)d_in[4];
    const float* emb_b2  = (const float*)d_in[5];
    const float* Wq      = (const float*)d_in[6];
    const float* Wk      = (const float*)d_in[7];
    const float* Wv      = (const float*)d_in[8];
    const float* ffn_W1  = (const float*)d_in[9];
    const float* ffn_W2  = (const float*)d_in[10];
    const float* bq      = (const float*)d_in[11];
    const float* bk      = (const float*)d_in[12];
    const float* bv      = (const float*)d_in[13];
    const float* ffn_b1  = (const float*)d_in[14];
    const float* ffn_b2  = (const float*)d_in[15];
    const float* n1_b    = (const float*)d_in[16];
    const float* n2_b    = (const float*)d_in[17];
    const float* n1_g    = (const float*)d_in[18];
    const float* n2_g    = (const float*)d_in[19];
    const float* u_W1    = (const float*)d_in[20];
    const float* u_b1    = (const float*)d_in[21];
    const float* u_W2    = (const float*)d_in[22];
    const float* u_b2    = (const float*)d_in[23];
    const float* u_g     = (const float*)d_in[24];
    const float* u_bb    = (const float*)d_in[25];
    const float* clf_W   = (const float*)d_in[26];
    const float* clf_b   = (const float*)d_in[27];
    const float* rec_W1  = (const float*)d_in[28];
    const float* rec_b1  = (const float*)d_in[29];
    const float* rec_W2  = (const float*)d_in[30];
    const float* rec_b2  = (const float*)d_in[31];
    const int* edge_index = (const int*)d_in[32];
    const int* batch     = (const int*)d_in[33];
    const int* srcI = edge_index;
    const int* dstI = edge_index + N_EDGES;

    float* out   = (float*)d_out;
    float* r_out = out + NGRAPH * NOUT_;

    // ---- workspace bump allocator (256B aligned) ----
    char* base = (char*)d_ws;
    size_t off = 0;
    auto alloc = [&](size_t bytes) -> char* {
        char* r = base + off;
        off += (bytes + 255) & ~(size_t)255;
        return r;
    };
    ushort* h16     = (ushort*)alloc((size_t)N_NODES * DD * 2);
    ushort* qkv16   = (ushort*)alloc((size_t)N_NODES * HH * 2);
    float*  agg     = (float*) alloc((size_t)N_NODES * DD * 4);   // agg,T16,h116 contiguous
    ushort* T16     = (ushort*)alloc((size_t)N_NODES * DD * 2);
    ushort* h116    = (ushort*)alloc((size_t)N_NODES * DD * 2);
    int2*   pe      = (int2*)  alloc((size_t)N_NODES * MAXDEG * 8); // pe,ae_slot contiguous
    float*  ae_slot = (float*) alloc((size_t)N_NODES * MAXDEG * 4);
    ushort* f116    = (ushort*)alloc((size_t)N_NODES * DD * 2);
    float*  denom   = (float*) alloc((size_t)N_NODES * 4);
    int*    deg     = (int*)   alloc((size_t)N_NODES * 4);
    float*  pooled  = (float*) alloc((size_t)NGRAPH * HH * 4);
    float*  cnt     = (float*) alloc(NGRAPH * 4);
    float*  Wcat    = (float*) alloc((size_t)NLAYERS * DD * 4 * DD * 4);
    float*  bcat    = (float*) alloc((size_t)NLAYERS * 4 * DD * 4);
    ushort* x16     = (ushort*)alloc((size_t)N_NODES * INF_ * 2);
    ushort* embW1T  = (ushort*)alloc((size_t)HH * INF_ * 2);
    ushort* embW2T  = (ushort*)alloc((size_t)DD * HH * 2);
    ushort* WcatT   = (ushort*)alloc((size_t)NLAYERS * HH * DD * 2);
    ushort* WvT     = (ushort*)alloc((size_t)NLAYERS * DD * DD * 2);
    ushort* fW1T    = (ushort*)alloc((size_t)NLAYERS * DD * DD * 2);
    ushort* fW2T    = (ushort*)alloc((size_t)NLAYERS * DD * DD * 2);
    ushort* uW1T    = (ushort*)alloc((size_t)HH * DD * 2);
    ushort* uW2T    = (ushort*)alloc((size_t)HH * HH * 2);
    ushort* recW1T  = (ushort*)alloc((size_t)HH * HH * 2);
    ushort* recW2T  = (ushort*)alloc((size_t)INF_ * HH * 2);
    ushort* ea16 = (ushort*)alloc((size_t)N_EDGES * DD * 2);
    bool use_ea16 = (ws_size >= off);
    const void* eaP = use_ea16 ? (const void*)ea16 : (const void*)ea;

    // head-phase aliases (layer buffers dead)
    ushort* t16    = qkv16;                 // 38.4 MB
    ushort* upre16 = (ushort*)agg;          // spans agg+T16+h116 = 38.4 MB
    ushort* u16    = (ushort*)pe;           // spans pe+ae_slot = 38.4 MB
    ushort* rtmp16 = qkv16;                 // t16 dead after u2

    dim3 blk(256);
    const int GB = (N_NODES + 127) / 128;   // 391
    const float scale = 1.f / sqrtf((float)DD);

    // ---- weight precompute/pack ----
    wqk_k<<<dim3(36, NLAYERS), blk, 0, stream>>>(Wq, Wk, bq, Wcat, bcat);
    pack_k<<<(NLAYERS * DD * 288 + 255) / 256, blk, 0, stream>>>(
        Wq, Wk, Wv, bq, bk, bv, Wcat, bcat);
    PackArgs pa;
    int pi = 0;
    auto addp = [&](const float* s, ushort* d, int K, int N) {
        pa.src[pi] = s; pa.dst[pi] = d; pa.K[pi] = K; pa.N[pi] = N; pi++;
    };
    addp(emb_W1, embW1T, INF_, HH);
    addp(emb_W2, embW2T, HH, DD);
    for (int l = 0; l < NLAYERS; l++) addp(Wcat + (size_t)l * DD * 4 * DD, WcatT + (size_t)l * HH * DD, DD, HH);
    for (int l = 0; l < NLAYERS; l++) addp(Wv + (size_t)l * DD * DD, WvT + (size_t)l * DD * DD, DD, DD);
    for (int l = 0; l < NLAYERS; l++) addp(ffn_W1 + (size_t)l * DD * DD, fW1T + (size_t)l * DD * DD, DD, DD);
    for (int l = 0; l < NLAYERS; l++) addp(ffn_W2 + (size_t)l * DD * DD, fW2T + (size_t)l * DD * DD, DD, DD);
    addp(u_W1, uW1T, DD, HH);
    addp(u_W2, uW2T, HH, HH);
    addp(rec_W1, recW1T, HH, HH);
    addp(rec_W2, recW2T, HH, INF_);
    packT_k<<<dim3(576, NPACK), blk, 0, stream>>>(pa);

    // ---- input converts ----
    cvt16<<<((size_t)N_NODES * INF_ / 4 + 255) / 256, blk, 0, stream>>>(
        x, x16, (long)N_NODES * INF_);
    if (use_ea16)
        cvt16<<<((size_t)N_EDGES * DD / 4 + 255) / 256, blk, 0, stream>>>(
            ea, ea16, (long)N_EDGES * DD);

    // ---- atom embedding MLP ----
    gemm_mf<128, ACT_RELU, false, true><<<dim3(GB, 3), blk, 0, stream>>>(
        x16, embW1T, emb_b1, nullptr, t16, N_NODES, HH, INF_);
    gemm_mf<96, ACT_NONE, false, true><<<dim3(GB, 1), blk, 0, stream>>>(
        t16, embW2T, emb_b2, nullptr, h16, N_NODES, DD, HH);

    // ---- adjacency build ----
    hipMemsetAsync(deg, 0, N_NODES * sizeof(int), stream);
    scatter_k<<<(N_EDGES + 255) / 256, blk, 0, stream>>>(srcI, dstI, deg, pe);

    // ---- RPETConv layers ----
    const int EGRID = (N_NODES + 3) / 4;
    for (int l = 0; l < NLAYERS; l++) {
        gemm_mf<128, ACT_NONE, false, true><<<dim3(GB, 3), blk, 0, stream>>>(
            h16, WcatT + (size_t)l * HH * DD, bcat + (size_t)l * 4 * DD,
            nullptr, qkv16, N_NODES, HH, DD);

        hipMemsetAsync(denom, 0, N_NODES * sizeof(float), stream);
        if (use_ea16) {
            edge1w<true><<<EGRID, blk, 0, stream>>>(
                qkv16, eaP, pe, deg, ae_slot, denom, scale);
            edge2w<true><<<EGRID, blk, 0, stream>>>(
                qkv16, eaP, ae_slot, denom, pe, deg, agg, T16);
        } else {
            edge1w<false><<<EGRID, blk, 0, stream>>>(
                qkv16, eaP, pe, deg, ae_slot, denom, scale);
            edge2w<false><<<EGRID, blk, 0, stream>>>(
                qkv16, eaP, ae_slot, denom, pe, deg, agg, T16);
        }

        // h116 = LN(h16 + agg + T@Wv)   (fused agg-GEMM + LayerNorm)
        gemm_ln<true><<<GB, blk, 0, stream>>>(
            T16, WvT + (size_t)l * DD * DD, nullptr, agg, h16,
            n1_g + (size_t)l * DD, n1_b + (size_t)l * DD, h116, N_NODES, DD);

        gemm_mf<96, ACT_ELU, false, true><<<dim3(GB, 1), blk, 0, stream>>>(
            h116, fW1T + (size_t)l * DD * DD, ffn_b1 + (size_t)l * DD,
            nullptr, f116, N_NODES, DD, DD);

        // h16 = LN(h116 + f116@W2 + b2)  (fused ffn2-GEMM + LayerNorm)
        gemm_ln<false><<<GB, blk, 0, stream>>>(
            f116, fW2T + (size_t)l * DD * DD, ffn_b2 + (size_t)l * DD,
            nullptr, h116, n2_g + (size_t)l * DD, n2_b + (size_t)l * DD,
            h16, N_NODES, DD);
    }

    // ---- updim + LN ----
    gemm_mf<128, ACT_LEAKY, false, true><<<dim3(GB, 3), blk, 0, stream>>>(
        h16, uW1T, u_b1, nullptr, t16, N_NODES, HH, DD);
    gemm_mf<128, ACT_NONE, false, true><<<dim3(GB, 3), blk, 0, stream>>>(
        t16, uW2T, u_b2, nullptr, upre16, N_NODES, HH, HH);
    ln_b<HH, 0><<<(N_NODES + 3) / 4, blk, 0, stream>>>(
        upre16, nullptr, u_g, u_bb, u16, N_NODES);

    // ---- mean pool + classifier ----
    hipMemsetAsync(pooled, 0, (size_t)(NGRAPH * HH + NGRAPH) * sizeof(float), stream);
    pool2_k<<<(N_NODES + PCHUNK - 1) / PCHUNK, 192, 0, stream>>>(u16, batch, pooled, cnt);
    clf_k<<<NGRAPH, 64, 0, stream>>>(pooled, cnt, clf_W, clf_b, out);

    // ---- reconstruction head ----
    gemm_mf<128, ACT_RELU, false, true><<<dim3(GB, 3), blk, 0, stream>>>(
        u16, recW1T, rec_b1, nullptr, rtmp16, N_NODES, HH, HH);
    gemm_mf<64, ACT_NONE, false, false><<<dim3(GB, 1), blk, 0, stream>>>(
        rtmp16, recW2T, rec_b2, r_out, nullptr, N_NODES, INF_, HH);
}